// Round 8
// baseline (192.747 us; speedup 1.0000x reference)
//
#include <hip/hip_runtime.h>
#include <hip/hip_bf16.h>
#include <math.h>

#define NB 2
#define EIN 4500
#define EOUT 9000
#define EPS 1e-5f

typedef __attribute__((ext_vector_type(8))) short bf16x8;
typedef __attribute__((ext_vector_type(4))) float f32x4;

__device__ inline uint32_t bfr(float x) {
    uint32_t u = __float_as_uint(x);
    return (u + 0x7fffu + ((u >> 16) & 1u)) >> 16;
}
__device__ inline uint32_t pk2(float a, float b) {
    __hip_bfloat162 h = __float22bfloat162_rn(make_float2(a, b));   // v_cvt_pk_bf16_f32
    uint32_t u;
    __builtin_memcpy(&u, &h, 4);
    return u;
}
__device__ inline float bf2f(ushort u) { return __uint_as_float((uint32_t)u << 16); }

// ---------- W pack into per-wave fragment order:
// Wq[((((w*NCH+ch)*4+ks)*2+ot)*64+lane)*8 + f], o=w*32+ot*16+(lane&15), c=ch*16+ks*4+(lane>>4)
__device__ inline void wpack_frag(const float* __restrict__ W, ushort* __restrict__ Wq,
                                  int i, int CIN) {
    int lane = i & 63; int t = i >> 6;
    int ot = t & 1; t >>= 1;
    int ks = t & 3; t >>= 2;
    int NCH = CIN / 16;
    int ch = t % NCH, w = t / NCH;
    int o = w * 32 + ot * 16 + (lane & 15);
    int c = ch * 16 + ks * 4 + (lane >> 4);
    const float* src = W + ((size_t)o * CIN + c) * 5;
    uint4 v;
    v.x = pk2(src[0], src[1]);
    v.y = pk2(src[2], src[3]);
    v.z = pk2(src[4], 0.f);
    v.w = 0u;
    *reinterpret_cast<uint4*>(Wq + (size_t)i * 8) = v;
}

// ---------- tiled transpose f32 [R][C] -> bf16 [C][R] (one 32x32 tile per call)
__device__ inline void transpose_bf_body(float (*tile)[33], const float* __restrict__ in,
                                         ushort* __restrict__ out, int R, int C,
                                         int id, int nbx, int nby, int tid) {
    int bxt = id % nbx; int rest = id / nbx;
    int by = rest % nby; int b = rest / nby;
    int c0 = bxt * 32, r0 = by * 32;
    const float* inb = in + (size_t)b * R * C;
    ushort* outb = out + (size_t)b * C * R;
    int tx = tid & 31, ty = tid >> 5;   // 32 x 8
#pragma unroll
    for (int i = 0; i < 4; ++i) {
        int r = r0 + ty + i * 8, c = c0 + tx;
        if (r < R && c < C) tile[ty + i * 8][tx] = inb[(size_t)r * C + c];
    }
    __syncthreads();
#pragma unroll
    for (int i = 0; i < 4; ++i) {
        int c = c0 + ty + i * 8, r = r0 + tx;
        if (r < R && c < C) outb[(size_t)c * R + r] = (ushort)bfr(tile[tx][ty + i * 8]);
    }
}

// ---------- prep: transposes + wpack + stats-zero (all independent; no parent/pval
// init needed: the scan writes every (b,eo) — unroll has exactly 1 nonzero/column)
#define FU_B 2256     // 141 x 8 x 2
#define FD_B 2256     // 282 x 4 x 2
#define WP_B 320      // 81920 / 256
#define INIT_B 1      // stats only (1024 floats)
__global__ __launch_bounds__(256) void prep_kernel(
    const float* __restrict__ from_up, ushort* __restrict__ FU,
    const float* __restrict__ from_down, ushort* __restrict__ FD,
    const float* __restrict__ W_up, ushort* __restrict__ Wq_up,
    const float* __restrict__ W1, ushort* __restrict__ Wq_1,
    const float* __restrict__ W2, ushort* __restrict__ Wq_2,
    float* __restrict__ stats) {
    __shared__ float tile[32][33];
    int bx = blockIdx.x, tid = threadIdx.x;
    if (bx < FU_B) {
        transpose_bf_body(tile, from_up, FU, 256, EIN, bx, 141, 8, tid);
    } else if (bx < FU_B + FD_B) {
        transpose_bf_body(tile, from_down, FD, 128, EOUT, bx - FU_B, 282, 4, tid);
    } else if (bx < FU_B + FD_B + WP_B) {
        int i = (bx - (FU_B + FD_B)) * 256 + tid;
        if (i < 32768) wpack_frag(W_up, Wq_up, i, 256);
        else if (i < 65536) wpack_frag(W1, Wq_1, i - 32768, 256);
        else wpack_frag(W2, Wq_2, i - 65536, 128);
    } else {
#pragma unroll
        for (int j = 0; j < 4; ++j) stats[j * 256 + tid] = 0.f;
    }
}

// ---------- coalesced 1-sparse column extraction of unroll_mat (grid-stride)
#define SCAN_B 2048
__device__ __forceinline__ void scan_body(int sbx, int tid,
                                          const float* __restrict__ mat,
                                          int* __restrict__ parent, float* __restrict__ pval) {
    const size_t total4 = (size_t)NB * EIN * EOUT / 4;
    const size_t stride = (size_t)SCAN_B * 256;
    for (size_t i = (size_t)sbx * 256 + tid; i < total4; i += stride) {
        float4 v = reinterpret_cast<const float4*>(mat)[i];
        if (v.x != 0.f || v.y != 0.f || v.z != 0.f || v.w != 0.f) {
            float a[4] = {v.x, v.y, v.z, v.w};
#pragma unroll
            for (int j = 0; j < 4; ++j) {
                if (a[j] != 0.f) {
                    size_t idx = i * 4 + j;
                    int eo = (int)(idx % EOUT);
                    size_t t = idx / EOUT;
                    int ei = (int)(t % EIN);
                    int b = (int)(t / EIN);
                    parent[b * EOUT + eo] = ei;
                    pval[b * EOUT + eo] = a[j];
                }
            }
        }
    }
}

// ---------- fused MFMA mesh conv body; double-buffered LDS, depth-2 reg prefetch.
// MODE 0: gather bf16 Xs[id][c]   MODE 1: unpool(Y1)+concat(FD)   MODE 2: relu(norm(Y2))
template <int CIN, int MODE, bool STATS>
__device__ __forceinline__ void conv_body(
    int ebx, int b, int tid,
    const ushort* __restrict__ Xs, const ushort* __restrict__ Aux,
    const int* __restrict__ gm, const int* __restrict__ parent,
    const float* __restrict__ pval, const float* __restrict__ stats_in,
    const ushort* __restrict__ Wq, const float* __restrict__ bias,
    ushort* __restrict__ Out, float* __restrict__ stats_out, int E) {
    constexpr int NCH = CIN / 16;      // 16-channel chunks; NCH is even (8 or 16)
    constexpr int LDW = 136;
    constexpr int GSZ = 64 * LDW;
    __shared__ __align__(16) ushort Gs[2 * GSZ];
    __shared__ int idx[320];
    __shared__ int par[MODE == 1 ? 320 : 1];
    __shared__ float pv[MODE == 1 ? 320 : 1];
    __shared__ float muS[MODE == 2 ? 128 : 1];
    __shared__ float rinvS[MODE == 2 ? 128 : 1];

    int e0 = ebx * 64;

    for (int i = tid; i < 320; i += 256) {
        int e = i / 5, k = i % 5;
        int eg = e0 + e;
        int id = (eg < E) ? gm[((size_t)b * E + eg) * 5 + k] : 0;
        idx[i] = id;
        if (MODE == 1) {
            par[i] = parent[b * EOUT + id];
            pv[i] = pval[b * EOUT + id];
        }
    }
    if (MODE == 2 && tid < 128) {
        float s = stats_in[(b * 128 + tid) * 2 + 0];
        float q = stats_in[(b * 128 + tid) * 2 + 1];
        float invE = 1.0f / (float)EOUT;
        float mu = s * invE;
        muS[tid] = mu;
        rinvS[tid] = rsqrtf(q * invE - mu * mu + EPS);
    }
    __syncthreads();

    int l = tid & 63, w = tid >> 6;
    int lr = l & 15, lg = l >> 4;
    int cg = tid & 3, eb = tid >> 2;
    bool evalid = (e0 + eb) < E;
    constexpr int XROW = (MODE == 0) ? CIN : 128;

    f32x4 acc[4][2];
#pragma unroll
    for (int et = 0; et < 4; ++et)
#pragma unroll
        for (int ot = 0; ot < 2; ++ot) acc[et][ot] = (f32x4)0.f;

    auto loadG = [&](int ch, uint2* g) {
        int c0 = ch * 16 + cg * 4;
#pragma unroll
        for (int k = 0; k < 5; ++k) {
            g[k] = make_uint2(0u, 0u);
            if (evalid) {
                int s5 = eb * 5 + k;
                const ushort* src;
                if (MODE == 1) {
                    if (ch < NCH / 2) src = Xs + ((size_t)b * EIN + par[s5]) * 128 + c0;
                    else src = Aux + ((size_t)b * EOUT + idx[s5]) * 128 + (c0 - 128);
                } else {
                    src = Xs + ((size_t)b * E + idx[s5]) * XROW + c0;
                }
                g[k] = *reinterpret_cast<const uint2*>(src);
            }
        }
    };

    auto stageG = [&](int ch, const uint2* g, ushort* gbuf) {
        float pvr[5];
        if (MODE == 1 && ch < NCH / 2) {
#pragma unroll
            for (int k = 0; k < 5; ++k) pvr[k] = pv[eb * 5 + k];
        }
#pragma unroll
        for (int j = 0; j < 4; ++j) {
            float f[5];
#pragma unroll
            for (int k = 0; k < 5; ++k) {
                uint32_t word = (j < 2) ? g[k].x : g[k].y;
                ushort h = (j & 1) ? (ushort)(word >> 16) : (ushort)(word & 0xffff);
                f[k] = bf2f(h);
            }
            if (MODE == 1 && ch < NCH / 2) {
#pragma unroll
                for (int k = 0; k < 5; ++k) f[k] *= pvr[k];
            } else if (MODE == 2) {
                int c = ch * 16 + cg * 4 + j;
                float mu = muS[c], rinv = rinvS[c];
#pragma unroll
                for (int k = 0; k < 5; ++k) {
                    float z = (f[k] - mu) * rinv;
                    f[k] = z > 0.f ? z : 0.f;
                }
            }
            uint4 v;
            v.x = pk2(f[0], f[1] + f[3]);
            v.y = pk2(f[2] + f[4], fabsf(f[1] - f[3]));
            v.z = pk2(fabsf(f[2] - f[4]), 0.f);
            v.w = 0u;
            *reinterpret_cast<uint4*>(gbuf + eb * LDW + (cg * 4 + j) * 8) = v;
        }
    };

    auto mfmaStep = [&](int ch, const ushort* gbuf) {
        const ushort* wbase = Wq + ((size_t)(w * NCH + ch) * 8 * 64 + l) * 8;
#pragma unroll
        for (int ks = 0; ks < 4; ++ks) {
            bf16x8 a[4], bb[2];
#pragma unroll
            for (int et = 0; et < 4; ++et)
                a[et] = *reinterpret_cast<const bf16x8*>(gbuf + (et * 16 + lr) * LDW + ks * 32 + lg * 8);
#pragma unroll
            for (int ot = 0; ot < 2; ++ot)
                bb[ot] = *reinterpret_cast<const bf16x8*>(wbase + ((size_t)(ks * 2 + ot) * 64) * 8);
#pragma unroll
            for (int et = 0; et < 4; ++et)
#pragma unroll
                for (int ot = 0; ot < 2; ++ot)
                    acc[et][ot] = __builtin_amdgcn_mfma_f32_16x16x32_bf16(a[et], bb[ot], acc[et][ot], 0, 0, 0);
        }
    };

    // software pipeline: loads 2 chunks ahead (covers HBM-miss latency);
    // LDS stays 2-buffer/1-barrier: buf[p] readers MFMA(ch) in (bar ch, bar ch+1),
    // writer stage(ch+2) in (bar ch+1, bar ch+2) — disjoint.
    uint2 gA[5], gB[5];
    loadG(0, gA);
    loadG(1, gB);
    for (int ch = 0; ch < NCH; ch += 2) {
        stageG(ch, gA, Gs);
        __syncthreads();
        if (ch + 2 < NCH) loadG(ch + 2, gA);
        mfmaStep(ch, Gs);

        stageG(ch + 1, gB, Gs + GSZ);
        __syncthreads();
        if (ch + 3 < NCH) loadG(ch + 3, gB);
        mfmaStep(ch + 1, Gs + GSZ);
    }

    // epilogue: D frag: col = lane&15 (=o), row = (lane>>4)*4 + r (=edge)
#pragma unroll
    for (int ot = 0; ot < 2; ++ot) {
        int o = w * 32 + ot * 16 + lr;
        float bv = bias[o];
        float s = 0.f, q = 0.f;
#pragma unroll
        for (int et = 0; et < 4; ++et) {
#pragma unroll
            for (int r = 0; r < 4; ++r) {
                int e = e0 + et * 16 + lg * 4 + r;
                if (e < E) {
                    float y = acc[et][ot][r] + bv;
                    Out[((size_t)b * E + e) * 128 + o] = (ushort)bfr(y);
                    if (STATS) { s += y; q += y * y; }
                }
            }
        }
        if (STATS) {
            s += __shfl_xor(s, 16, 64); s += __shfl_xor(s, 32, 64);
            q += __shfl_xor(q, 16, 64); q += __shfl_xor(q, 32, 64);
            if (lg == 0) {
                atomicAdd(&stats_out[(b * 128 + o) * 2 + 0], s);
                atomicAdd(&stats_out[(b * 128 + o) * 2 + 1], q);
            }
        }
    }
}

// ---------- dispatch 2: up-conv blocks (first, latency/MFMA-bound) co-scheduled
// with the HBM-bound scan blocks — complementary pipes overlap (m114).
#define UP_B 142      // 71 x 2
__global__ __launch_bounds__(256) void scan_upconv_kernel(
    const float* __restrict__ unroll, int* __restrict__ parent, float* __restrict__ pval,
    const ushort* __restrict__ FU, const int* __restrict__ gemm_up,
    const ushort* __restrict__ Wq_up, const float* __restrict__ b_up,
    ushort* __restrict__ Y1) {
    int bx = blockIdx.x, tid = threadIdx.x;
    if (bx < UP_B) {
        conv_body<256, 0, false>(bx % 71, bx / 71, tid, FU, nullptr, gemm_up,
                                 nullptr, nullptr, nullptr, Wq_up, b_up, Y1, nullptr, EIN);
    } else {
        scan_body(bx - UP_B, tid, unroll, parent, pval);
    }
}

template <int CIN, int MODE, bool STATS>
__global__ __launch_bounds__(256) void conv_mfma(
    const ushort* __restrict__ Xs, const ushort* __restrict__ Aux,
    const int* __restrict__ gm, const int* __restrict__ parent,
    const float* __restrict__ pval, const float* __restrict__ stats_in,
    const ushort* __restrict__ Wq, const float* __restrict__ bias,
    ushort* __restrict__ Out, float* __restrict__ stats_out, int E) {
    conv_body<CIN, MODE, STATS>(blockIdx.x, blockIdx.y, threadIdx.x,
                                Xs, Aux, gm, parent, pval, stats_in, Wq, bias,
                                Out, stats_out, E);
}

// ---------- out[b][c][e] = relu( norm2(Y3) + relu(norm1(Y2)) ), bf16 -> f32 ch-major
__global__ void final_kernel(const ushort* __restrict__ Y3, const ushort* __restrict__ Y2,
                             const float* __restrict__ stats1, const float* __restrict__ stats2,
                             float* __restrict__ out, int E) {
    __shared__ float tile[32 * 129];
    int b = blockIdx.y;
    int e0 = blockIdx.x * 32;
    int tid = threadIdx.x;
    float invE = 1.0f / (float)E;
#pragma unroll
    for (int i = 0; i < 16; ++i) {
        int idx = i * 256 + tid;
        int c = idx & 127, el = idx >> 7;
        int e = e0 + el;
        float v = 0.f;
        if (e < E) {
            float s1 = stats1[(b * 128 + c) * 2 + 0], q1 = stats1[(b * 128 + c) * 2 + 1];
            float mu1 = s1 * invE, var1 = q1 * invE - mu1 * mu1;
            float s2 = stats2[(b * 128 + c) * 2 + 0], q2 = stats2[(b * 128 + c) * 2 + 1];
            float mu2 = s2 * invE, var2 = q2 * invE - mu2 * mu2;
            float x1 = (bf2f(Y2[((size_t)b * E + e) * 128 + c]) - mu1) * rsqrtf(var1 + EPS);
            x1 = x1 > 0.f ? x1 : 0.f;
            float z = (bf2f(Y3[((size_t)b * E + e) * 128 + c]) - mu2) * rsqrtf(var2 + EPS);
            v = z + x1;
            v = v > 0.f ? v : 0.f;
        }
        tile[el * 129 + c] = v;
    }
    __syncthreads();
#pragma unroll
    for (int i = 0; i < 16; ++i) {
        int idx = i * 256 + tid;
        int el = idx & 31, c = idx >> 5;
        int e = e0 + el;
        if (e < E) out[((size_t)b * 128 + c) * E + e] = tile[el * 129 + c];
    }
}

extern "C" void kernel_launch(void* const* d_in, const int* in_sizes, int n_in,
                              void* d_out, int out_size, void* d_ws, size_t ws_size,
                              hipStream_t stream) {
    const float* from_up   = (const float*)d_in[0];
    const float* from_down = (const float*)d_in[1];
    const float* unroll    = (const float*)d_in[2];
    const float* W_up      = (const float*)d_in[3];
    const float* b_up      = (const float*)d_in[4];
    const float* W1        = (const float*)d_in[5];
    const float* b1        = (const float*)d_in[6];
    const float* W2        = (const float*)d_in[7];
    const float* b2        = (const float*)d_in[8];
    const int* gemm_up     = (const int*)d_in[9];
    const int* gemm_post   = (const int*)d_in[10];
    float* out = (float*)d_out;

    float* ws = (float*)d_ws;
    size_t off = 0;
    auto alloc = [&](size_t n) { float* p = ws + off; off += n; return p; };
    ushort* FU_bf = (ushort*)alloc((size_t)NB * EIN * 256 / 2);   // [B][EIN][256] bf16
    ushort* FD_bf = (ushort*)alloc((size_t)NB * EOUT * 128 / 2);  // [B][EOUT][128] bf16
    ushort* Wq_up = (ushort*)alloc(131072);                       // frag order
    ushort* Wq_1  = (ushort*)alloc(131072);
    ushort* Wq_2  = (ushort*)alloc(65536);
    ushort* Y1_bf = (ushort*)alloc((size_t)NB * EIN * 128 / 2);
    ushort* Y2_bf = (ushort*)alloc((size_t)NB * EOUT * 128 / 2);
    ushort* Y3_bf = (ushort*)alloc((size_t)NB * EOUT * 128 / 2);
    float* stats  = alloc(1024);
    int*   parent = (int*)alloc(NB * EOUT);
    float* pval   = alloc(NB * EOUT);
    float* stats1 = stats, *stats2 = stats + 512;

    // 1: independent prep (transposes, weight packs, stats zero)
    prep_kernel<<<FU_B + FD_B + WP_B + INIT_B, 256, 0, stream>>>(
        from_up, FU_bf, from_down, FD_bf, W_up, Wq_up, W1, Wq_1, W2, Wq_2, stats);
    // 2: scan (HBM-bound) overlapped with up-conv (MFMA/latency-bound)
    scan_upconv_kernel<<<UP_B + SCAN_B, 256, 0, stream>>>(
        unroll, parent, pval, FU_bf, gemm_up, Wq_up, b_up, Y1_bf);
    // 3: conv1 (fused unpool+concat gather, fused stats1)
    conv_mfma<256, 1, true><<<dim3(141, NB), 256, 0, stream>>>(
        Y1_bf, FD_bf, gemm_post, parent, pval, nullptr, Wq_1, b1, Y2_bf, stats1, EOUT);
    // 4: conv2 (fused norm+relu gather, fused stats2)
    conv_mfma<128, 2, true><<<dim3(141, NB), 256, 0, stream>>>(
        Y2_bf, nullptr, gemm_post, nullptr, nullptr, stats1, Wq_2, b2, Y3_bf, stats2, EOUT);
    // 5: final: norm2 + residual + relu + transpose to [B][C][E] f32
    final_kernel<<<dim3(282, NB), 256, 0, stream>>>(Y3_bf, Y2_bf, stats1, stats2, out, EOUT);
}

// Round 12
// 182.854 us; speedup vs baseline: 1.0541x; 1.0541x over previous
//
#include <hip/hip_runtime.h>
#include <hip/hip_bf16.h>
#include <math.h>

#define NB 2
#define EIN 4500
#define EOUT 9000
#define EPS 1e-5f

typedef __attribute__((ext_vector_type(8))) short bf16x8;
typedef __attribute__((ext_vector_type(4))) float f32x4;

__device__ inline uint32_t bfr(float x) {
    uint32_t u = __float_as_uint(x);
    return (u + 0x7fffu + ((u >> 16) & 1u)) >> 16;
}
__device__ inline uint32_t pk2(float a, float b) {
    __hip_bfloat162 h = __float22bfloat162_rn(make_float2(a, b));   // v_cvt_pk_bf16_f32
    uint32_t u;
    __builtin_memcpy(&u, &h, 4);
    return u;
}
__device__ inline float bf2f(ushort u) { return __uint_as_float((uint32_t)u << 16); }

// ---------- W pack into per-wave fragment order:
// Wq[((((w*NCH+ch)*4+ks)*2+ot)*64+lane)*8 + f], o=w*32+ot*16+(lane&15), c=ch*16+ks*4+(lane>>4)
__device__ inline void wpack_frag(const float* __restrict__ W, ushort* __restrict__ Wq,
                                  int i, int CIN) {
    int lane = i & 63; int t = i >> 6;
    int ot = t & 1; t >>= 1;
    int ks = t & 3; t >>= 2;
    int NCH = CIN / 16;
    int ch = t % NCH, w = t / NCH;
    int o = w * 32 + ot * 16 + (lane & 15);
    int c = ch * 16 + ks * 4 + (lane >> 4);
    const float* src = W + ((size_t)o * CIN + c) * 5;
    uint4 v;
    v.x = pk2(src[0], src[1]);
    v.y = pk2(src[2], src[3]);
    v.z = pk2(src[4], 0.f);
    v.w = 0u;
    *reinterpret_cast<uint4*>(Wq + (size_t)i * 8) = v;
}

// ---------- tiled transpose f32 [R][C] -> bf16 [C][R] (one 32x32 tile per call)
__device__ inline void transpose_bf_body(float (*tile)[33], const float* __restrict__ in,
                                         ushort* __restrict__ out, int R, int C,
                                         int id, int nbx, int nby, int tid) {
    int bxt = id % nbx; int rest = id / nbx;
    int by = rest % nby; int b = rest / nby;
    int c0 = bxt * 32, r0 = by * 32;
    const float* inb = in + (size_t)b * R * C;
    ushort* outb = out + (size_t)b * C * R;
    int tx = tid & 31, ty = tid >> 5;   // 32 x 8
#pragma unroll
    for (int i = 0; i < 4; ++i) {
        int r = r0 + ty + i * 8, c = c0 + tx;
        if (r < R && c < C) tile[ty + i * 8][tx] = inb[(size_t)r * C + c];
    }
    __syncthreads();
#pragma unroll
    for (int i = 0; i < 4; ++i) {
        int c = c0 + ty + i * 8, r = r0 + tx;
        if (r < R && c < C) outb[(size_t)c * R + r] = (ushort)bfr(tile[tx][ty + i * 8]);
    }
}

// ---------- phase0: scan + transposes + wpack + stats-zero fused.
// NOTE: parent/pval are NOT zero-initialized — the unpool matrix has exactly one
// nonzero per column, so the scan overwrites every (b,eo) deterministically.
// (Zeroing them here raced with the scan in R6 — blocks run in undefined order.)
#define SCAN_B 2048
#define FU_B 2256     // 141 x 8 x 2
#define FD_B 2256     // 282 x 4 x 2
#define WP_B 320      // 81920 / 256
#define INIT_B 1      // stats only (1024 floats)
__global__ __launch_bounds__(256) void phase0_kernel(
    const float* __restrict__ unroll, int* __restrict__ parent, float* __restrict__ pval,
    const float* __restrict__ from_up, ushort* __restrict__ FU,
    const float* __restrict__ from_down, ushort* __restrict__ FD,
    const float* __restrict__ W_up, ushort* __restrict__ Wq_up,
    const float* __restrict__ W1, ushort* __restrict__ Wq_1,
    const float* __restrict__ W2, ushort* __restrict__ Wq_2,
    float* __restrict__ stats) {
    __shared__ float tile[32][33];
    int bx = blockIdx.x, tid = threadIdx.x;
    if (bx < SCAN_B) {
        const size_t total4 = (size_t)NB * EIN * EOUT / 4;
        const size_t stride = (size_t)SCAN_B * 256;
        for (size_t i = (size_t)bx * 256 + tid; i < total4; i += stride) {
            float4 v = reinterpret_cast<const float4*>(unroll)[i];
            if (v.x != 0.f || v.y != 0.f || v.z != 0.f || v.w != 0.f) {
                float a[4] = {v.x, v.y, v.z, v.w};
#pragma unroll
                for (int j = 0; j < 4; ++j) {
                    if (a[j] != 0.f) {
                        size_t idx = i * 4 + j;
                        int eo = (int)(idx % EOUT);
                        size_t t = idx / EOUT;
                        int ei = (int)(t % EIN);
                        int b = (int)(t / EIN);
                        parent[b * EOUT + eo] = ei;
                        pval[b * EOUT + eo] = a[j];
                    }
                }
            }
        }
    } else if (bx < SCAN_B + FU_B) {
        transpose_bf_body(tile, from_up, FU, 256, EIN, bx - SCAN_B, 141, 8, tid);
    } else if (bx < SCAN_B + FU_B + FD_B) {
        transpose_bf_body(tile, from_down, FD, 128, EOUT, bx - (SCAN_B + FU_B), 282, 4, tid);
    } else if (bx < SCAN_B + FU_B + FD_B + WP_B) {
        int i = (bx - (SCAN_B + FU_B + FD_B)) * 256 + tid;
        if (i < 32768) wpack_frag(W_up, Wq_up, i, 256);
        else if (i < 65536) wpack_frag(W1, Wq_1, i - 32768, 256);
        else wpack_frag(W2, Wq_2, i - 65536, 128);
    } else {
        // stats zero (required every call: conv epilogues accumulate atomically)
#pragma unroll
        for (int j = 0; j < 4; ++j) stats[j * 256 + tid] = 0.f;
    }
}

// ---------- fused MFMA mesh conv, double-buffered LDS, 1 barrier/chunk.
// MODE 0: gather bf16 Xs[id][c]   MODE 1: unpool(Y1)+concat(FD)   MODE 2: relu(norm(Y2))
template <int CIN, int MODE, bool STATS>
__global__ __launch_bounds__(256) void conv_mfma(
    const ushort* __restrict__ Xs, const ushort* __restrict__ Aux,
    const int* __restrict__ gm, const int* __restrict__ parent,
    const float* __restrict__ pval, const float* __restrict__ stats_in,
    const ushort* __restrict__ Wq, const float* __restrict__ bias,
    ushort* __restrict__ Out, float* __restrict__ stats_out, int E) {
    constexpr int NCH = CIN / 16;
    constexpr int LDW = 136;
    constexpr int GSZ = 64 * LDW;
    __shared__ __align__(16) ushort Gs[2 * GSZ];
    __shared__ int idx[320];
    __shared__ int par[MODE == 1 ? 320 : 1];
    __shared__ float pv[MODE == 1 ? 320 : 1];
    __shared__ float muS[MODE == 2 ? 128 : 1];
    __shared__ float rinvS[MODE == 2 ? 128 : 1];

    int tid = threadIdx.x;
    int b = blockIdx.y, e0 = blockIdx.x * 64;

    for (int i = tid; i < 320; i += 256) {
        int e = i / 5, k = i % 5;
        int eg = e0 + e;
        int id = (eg < E) ? gm[((size_t)b * E + eg) * 5 + k] : 0;
        idx[i] = id;
        if (MODE == 1) {
            par[i] = parent[b * EOUT + id];
            pv[i] = pval[b * EOUT + id];
        }
    }
    if (MODE == 2 && tid < 128) {
        float s = stats_in[(b * 128 + tid) * 2 + 0];
        float q = stats_in[(b * 128 + tid) * 2 + 1];
        float invE = 1.0f / (float)EOUT;
        float mu = s * invE;
        muS[tid] = mu;
        rinvS[tid] = rsqrtf(q * invE - mu * mu + EPS);
    }
    __syncthreads();

    int l = tid & 63, w = tid >> 6;
    int lr = l & 15, lg = l >> 4;
    int cg = tid & 3, eb = tid >> 2;
    bool evalid = (e0 + eb) < E;
    constexpr int XROW = (MODE == 0) ? CIN : 128;

    f32x4 acc[4][2];
#pragma unroll
    for (int et = 0; et < 4; ++et)
#pragma unroll
        for (int ot = 0; ot < 2; ++ot) acc[et][ot] = (f32x4)0.f;

    uint2 g[5];
    auto loadG = [&](int ch) {
        int c0 = ch * 16 + cg * 4;
#pragma unroll
        for (int k = 0; k < 5; ++k) {
            g[k] = make_uint2(0u, 0u);
            if (evalid) {
                int s5 = eb * 5 + k;
                const ushort* src;
                if (MODE == 1) {
                    if (ch < NCH / 2) src = Xs + ((size_t)b * EIN + par[s5]) * 128 + c0;
                    else src = Aux + ((size_t)b * EOUT + idx[s5]) * 128 + (c0 - 128);
                } else {
                    src = Xs + ((size_t)b * E + idx[s5]) * XROW + c0;
                }
                g[k] = *reinterpret_cast<const uint2*>(src);
            }
        }
    };

    auto stageG = [&](int ch, ushort* gbuf) {
        float pvr[5];
        if (MODE == 1 && ch < NCH / 2) {
#pragma unroll
            for (int k = 0; k < 5; ++k) pvr[k] = pv[eb * 5 + k];
        }
#pragma unroll
        for (int j = 0; j < 4; ++j) {
            float f[5];
#pragma unroll
            for (int k = 0; k < 5; ++k) {
                uint32_t word = (j < 2) ? g[k].x : g[k].y;
                ushort h = (j & 1) ? (ushort)(word >> 16) : (ushort)(word & 0xffff);
                f[k] = bf2f(h);
            }
            if (MODE == 1 && ch < NCH / 2) {
#pragma unroll
                for (int k = 0; k < 5; ++k) f[k] *= pvr[k];
            } else if (MODE == 2) {
                int c = ch * 16 + cg * 4 + j;
                float mu = muS[c], rinv = rinvS[c];
#pragma unroll
                for (int k = 0; k < 5; ++k) {
                    float z = (f[k] - mu) * rinv;
                    f[k] = z > 0.f ? z : 0.f;
                }
            }
            uint4 v;
            v.x = pk2(f[0], f[1] + f[3]);
            v.y = pk2(f[2] + f[4], fabsf(f[1] - f[3]));
            v.z = pk2(fabsf(f[2] - f[4]), 0.f);
            v.w = 0u;
            *reinterpret_cast<uint4*>(gbuf + eb * LDW + (cg * 4 + j) * 8) = v;
        }
    };

    loadG(0);
    for (int ch = 0; ch < NCH; ++ch) {
        ushort* gbuf = Gs + (ch & 1) * GSZ;
        stageG(ch, gbuf);             // write buf[ch&1]: prior reader MFMA(ch-2) fenced by bar(ch-1)
        __syncthreads();
        if (ch + 1 < NCH) loadG(ch + 1);   // issue next gathers; latency hides under MFMA
        const ushort* wbase = Wq + ((size_t)(w * NCH + ch) * 8 * 64 + l) * 8;
#pragma unroll
        for (int ks = 0; ks < 4; ++ks) {
            bf16x8 a[4], bb[2];
#pragma unroll
            for (int et = 0; et < 4; ++et)
                a[et] = *reinterpret_cast<const bf16x8*>(gbuf + (et * 16 + lr) * LDW + ks * 32 + lg * 8);
#pragma unroll
            for (int ot = 0; ot < 2; ++ot)
                bb[ot] = *reinterpret_cast<const bf16x8*>(wbase + ((size_t)(ks * 2 + ot) * 64) * 8);
#pragma unroll
            for (int et = 0; et < 4; ++et)
#pragma unroll
                for (int ot = 0; ot < 2; ++ot)
                    acc[et][ot] = __builtin_amdgcn_mfma_f32_16x16x32_bf16(a[et], bb[ot], acc[et][ot], 0, 0, 0);
        }
    }

    // epilogue: D frag: col = lane&15 (=o), row = (lane>>4)*4 + r (=edge)
#pragma unroll
    for (int ot = 0; ot < 2; ++ot) {
        int o = w * 32 + ot * 16 + lr;
        float bv = bias[o];
        float s = 0.f, q = 0.f;
#pragma unroll
        for (int et = 0; et < 4; ++et) {
#pragma unroll
            for (int r = 0; r < 4; ++r) {
                int e = e0 + et * 16 + lg * 4 + r;
                if (e < E) {
                    float y = acc[et][ot][r] + bv;
                    Out[((size_t)b * E + e) * 128 + o] = (ushort)bfr(y);
                    if (STATS) { s += y; q += y * y; }
                }
            }
        }
        if (STATS) {
            s += __shfl_xor(s, 16, 64); s += __shfl_xor(s, 32, 64);
            q += __shfl_xor(q, 16, 64); q += __shfl_xor(q, 32, 64);
            if (lg == 0) {
                atomicAdd(&stats_out[(b * 128 + o) * 2 + 0], s);
                atomicAdd(&stats_out[(b * 128 + o) * 2 + 1], q);
            }
        }
    }
}

// ---------- out[b][c][e] = relu( norm2(Y3) + relu(norm1(Y2)) ), bf16 -> f32 ch-major
__global__ void final_kernel(const ushort* __restrict__ Y3, const ushort* __restrict__ Y2,
                             const float* __restrict__ stats1, const float* __restrict__ stats2,
                             float* __restrict__ out, int E) {
    __shared__ float tile[32 * 129];
    int b = blockIdx.y;
    int e0 = blockIdx.x * 32;
    int tid = threadIdx.x;
    float invE = 1.0f / (float)E;
#pragma unroll
    for (int i = 0; i < 16; ++i) {
        int idx = i * 256 + tid;
        int c = idx & 127, el = idx >> 7;
        int e = e0 + el;
        float v = 0.f;
        if (e < E) {
            float s1 = stats1[(b * 128 + c) * 2 + 0], q1 = stats1[(b * 128 + c) * 2 + 1];
            float mu1 = s1 * invE, var1 = q1 * invE - mu1 * mu1;
            float s2 = stats2[(b * 128 + c) * 2 + 0], q2 = stats2[(b * 128 + c) * 2 + 1];
            float mu2 = s2 * invE, var2 = q2 * invE - mu2 * mu2;
            float x1 = (bf2f(Y2[((size_t)b * E + e) * 128 + c]) - mu1) * rsqrtf(var1 + EPS);
            x1 = x1 > 0.f ? x1 : 0.f;
            float z = (bf2f(Y3[((size_t)b * E + e) * 128 + c]) - mu2) * rsqrtf(var2 + EPS);
            v = z + x1;
            v = v > 0.f ? v : 0.f;
        }
        tile[el * 129 + c] = v;
    }
    __syncthreads();
#pragma unroll
    for (int i = 0; i < 16; ++i) {
        int idx = i * 256 + tid;
        int el = idx & 31, c = idx >> 5;
        int e = e0 + el;
        if (e < E) out[((size_t)b * 128 + c) * E + e] = tile[el * 129 + c];
    }
}

extern "C" void kernel_launch(void* const* d_in, const int* in_sizes, int n_in,
                              void* d_out, int out_size, void* d_ws, size_t ws_size,
                              hipStream_t stream) {
    const float* from_up   = (const float*)d_in[0];
    const float* from_down = (const float*)d_in[1];
    const float* unroll    = (const float*)d_in[2];
    const float* W_up      = (const float*)d_in[3];
    const float* b_up      = (const float*)d_in[4];
    const float* W1        = (const float*)d_in[5];
    const float* b1        = (const float*)d_in[6];
    const float* W2        = (const float*)d_in[7];
    const float* b2        = (const float*)d_in[8];
    const int* gemm_up     = (const int*)d_in[9];
    const int* gemm_post   = (const int*)d_in[10];
    float* out = (float*)d_out;

    float* ws = (float*)d_ws;
    size_t off = 0;
    auto alloc = [&](size_t n) { float* p = ws + off; off += n; return p; };
    ushort* FU_bf = (ushort*)alloc((size_t)NB * EIN * 256 / 2);   // [B][EIN][256] bf16
    ushort* FD_bf = (ushort*)alloc((size_t)NB * EOUT * 128 / 2);  // [B][EOUT][128] bf16
    ushort* Wq_up = (ushort*)alloc(131072);                       // frag order
    ushort* Wq_1  = (ushort*)alloc(131072);
    ushort* Wq_2  = (ushort*)alloc(65536);
    ushort* Y1_bf = (ushort*)alloc((size_t)NB * EIN * 128 / 2);
    ushort* Y2_bf = (ushort*)alloc((size_t)NB * EOUT * 128 / 2);
    ushort* Y3_bf = (ushort*)alloc((size_t)NB * EOUT * 128 / 2);
    float* stats  = alloc(1024);
    int*   parent = (int*)alloc(NB * EOUT);
    float* pval   = alloc(NB * EOUT);
    float* stats1 = stats, *stats2 = stats + 512;

    phase0_kernel<<<SCAN_B + FU_B + FD_B + WP_B + INIT_B, 256, 0, stream>>>(
        unroll, parent, pval, from_up, FU_bf, from_down, FD_bf,
        W_up, Wq_up, W1, Wq_1, W2, Wq_2, stats);

    // up conv: FU_bf -> Y1_bf
    conv_mfma<256, 0, false><<<dim3(71, NB), 256, 0, stream>>>(
        FU_bf, nullptr, gemm_up, nullptr, nullptr, nullptr, Wq_up, b_up, Y1_bf, nullptr, EIN);
    // conv1 (fused unpool+concat gather, fused stats1): -> Y2_bf
    conv_mfma<256, 1, true><<<dim3(141, NB), 256, 0, stream>>>(
        Y1_bf, FD_bf, gemm_post, parent, pval, nullptr, Wq_1, b1, Y2_bf, stats1, EOUT);
    // conv2 (fused norm+relu gather, fused stats2): -> Y3_bf
    conv_mfma<128, 2, true><<<dim3(141, NB), 256, 0, stream>>>(
        Y2_bf, nullptr, gemm_post, nullptr, nullptr, stats1, Wq_2, b2, Y3_bf, stats2, EOUT);
    // final: norm2 + residual + relu + transpose to [B][C][E] f32
    final_kernel<<<dim3(282, NB), 256, 0, stream>>>(Y3_bf, Y2_bf, stats1, stats2, out, EOUT);
}

// Round 13
// 165.854 us; speedup vs baseline: 1.1622x; 1.1025x over previous
//
#include <hip/hip_runtime.h>
#include <hip/hip_bf16.h>
#include <math.h>

#define NB 2
#define EIN 4500
#define EOUT 9000
#define EPS 1e-5f

typedef __attribute__((ext_vector_type(8))) short bf16x8;
typedef __attribute__((ext_vector_type(4))) float f32x4;

__device__ inline uint32_t bfr(float x) {
    uint32_t u = __float_as_uint(x);
    return (u + 0x7fffu + ((u >> 16) & 1u)) >> 16;
}
__device__ inline uint32_t pk2(float a, float b) {
    __hip_bfloat162 h = __float22bfloat162_rn(make_float2(a, b));   // v_cvt_pk_bf16_f32
    uint32_t u;
    __builtin_memcpy(&u, &h, 4);
    return u;
}
__device__ inline float bf2f(ushort u) { return __uint_as_float((uint32_t)u << 16); }

// ---------- W pack into per-wave fragment order (UNCHANGED layout from R12):
// Wq[((((w4*NCH16+g)*4+ks)*2+ot)*64+lane)*8 + f], o=w4*32+ot*16+(lane&15), c=g*16+ks*4+(lane>>4)
__device__ inline void wpack_frag(const float* __restrict__ W, ushort* __restrict__ Wq,
                                  int i, int CIN) {
    int lane = i & 63; int t = i >> 6;
    int ot = t & 1; t >>= 1;
    int ks = t & 3; t >>= 2;
    int NCH = CIN / 16;
    int ch = t % NCH, w = t / NCH;
    int o = w * 32 + ot * 16 + (lane & 15);
    int c = ch * 16 + ks * 4 + (lane >> 4);
    const float* src = W + ((size_t)o * CIN + c) * 5;
    uint4 v;
    v.x = pk2(src[0], src[1]);
    v.y = pk2(src[2], src[3]);
    v.z = pk2(src[4], 0.f);
    v.w = 0u;
    *reinterpret_cast<uint4*>(Wq + (size_t)i * 8) = v;
}

// ---------- tiled transpose f32 [R][C] -> bf16 [C][R] (one 32x32 tile per call)
__device__ inline void transpose_bf_body(float (*tile)[33], const float* __restrict__ in,
                                         ushort* __restrict__ out, int R, int C,
                                         int id, int nbx, int nby, int tid) {
    int bxt = id % nbx; int rest = id / nbx;
    int by = rest % nby; int b = rest / nby;
    int c0 = bxt * 32, r0 = by * 32;
    const float* inb = in + (size_t)b * R * C;
    ushort* outb = out + (size_t)b * C * R;
    int tx = tid & 31, ty = tid >> 5;   // 32 x 8
#pragma unroll
    for (int i = 0; i < 4; ++i) {
        int r = r0 + ty + i * 8, c = c0 + tx;
        if (r < R && c < C) tile[ty + i * 8][tx] = inb[(size_t)r * C + c];
    }
    __syncthreads();
#pragma unroll
    for (int i = 0; i < 4; ++i) {
        int c = c0 + ty + i * 8, r = r0 + tx;
        if (r < R && c < C) outb[(size_t)c * R + r] = (ushort)bfr(tile[tx][ty + i * 8]);
    }
}

// ---------- phase0: scan + transposes + wpack + stats-zero fused (R12-identical).
#define SCAN_B 2048
#define FU_B 2256     // 141 x 8 x 2
#define FD_B 2256     // 282 x 4 x 2
#define WP_B 320      // 81920 / 256
#define INIT_B 1      // stats only (1024 floats)
__global__ __launch_bounds__(256) void phase0_kernel(
    const float* __restrict__ unroll, int* __restrict__ parent, float* __restrict__ pval,
    const float* __restrict__ from_up, ushort* __restrict__ FU,
    const float* __restrict__ from_down, ushort* __restrict__ FD,
    const float* __restrict__ W_up, ushort* __restrict__ Wq_up,
    const float* __restrict__ W1, ushort* __restrict__ Wq_1,
    const float* __restrict__ W2, ushort* __restrict__ Wq_2,
    float* __restrict__ stats) {
    __shared__ float tile[32][33];
    int bx = blockIdx.x, tid = threadIdx.x;
    if (bx < SCAN_B) {
        const size_t total4 = (size_t)NB * EIN * EOUT / 4;
        const size_t stride = (size_t)SCAN_B * 256;
        for (size_t i = (size_t)bx * 256 + tid; i < total4; i += stride) {
            float4 v = reinterpret_cast<const float4*>(unroll)[i];
            if (v.x != 0.f || v.y != 0.f || v.z != 0.f || v.w != 0.f) {
                float a[4] = {v.x, v.y, v.z, v.w};
#pragma unroll
                for (int j = 0; j < 4; ++j) {
                    if (a[j] != 0.f) {
                        size_t idx = i * 4 + j;
                        int eo = (int)(idx % EOUT);
                        size_t t = idx / EOUT;
                        int ei = (int)(t % EIN);
                        int b = (int)(t / EIN);
                        parent[b * EOUT + eo] = ei;
                        pval[b * EOUT + eo] = a[j];
                    }
                }
            }
        }
    } else if (bx < SCAN_B + FU_B) {
        transpose_bf_body(tile, from_up, FU, 256, EIN, bx - SCAN_B, 141, 8, tid);
    } else if (bx < SCAN_B + FU_B + FD_B) {
        transpose_bf_body(tile, from_down, FD, 128, EOUT, bx - (SCAN_B + FU_B), 282, 4, tid);
    } else if (bx < SCAN_B + FU_B + FD_B + WP_B) {
        int i = (bx - (SCAN_B + FU_B + FD_B)) * 256 + tid;
        if (i < 32768) wpack_frag(W_up, Wq_up, i, 256);
        else if (i < 65536) wpack_frag(W1, Wq_1, i - 32768, 256);
        else wpack_frag(W2, Wq_2, i - 65536, 128);
    } else {
#pragma unroll
        for (int j = 0; j < 4; ++j) stats[j * 256 + tid] = 0.f;
    }
}

// ---------- fused MFMA mesh conv: 64 edges x 128 outs per block, 8 waves (512 thr),
// 32-ch chunks, double-buffered LDS, depth-1 prefetch, 1 barrier/chunk.
// Same grid + same atomic-stats pattern as R12; only intra-block parallelism changed.
// MODE 0: gather bf16 Xs[id][c]   MODE 1: unpool(Y1)+concat(FD)   MODE 2: relu(norm(Y2))
template <int CIN, int MODE, bool STATS>
__global__ __launch_bounds__(512, 4) void conv_mfma(
    const ushort* __restrict__ Xs, const ushort* __restrict__ Aux,
    const int* __restrict__ gm, const int* __restrict__ parent,
    const float* __restrict__ pval, const float* __restrict__ stats_in,
    const ushort* __restrict__ Wq, const float* __restrict__ bias,
    ushort* __restrict__ Out, float* __restrict__ stats_out, int E) {
    constexpr int NCH16 = CIN / 16;   // Wq layout granularity
    constexpr int NCH = CIN / 32;     // 32-channel chunks
    constexpr int LDW = 264;          // 256 k' + 8 pad (bf16) per edge-row
    constexpr int GSZ = 64 * LDW;
    __shared__ __align__(16) ushort Gs[2 * GSZ];
    __shared__ int idx[320];
    __shared__ int par[MODE == 1 ? 320 : 1];
    __shared__ float pv[MODE == 1 ? 320 : 1];
    __shared__ float muS[MODE == 2 ? 128 : 1];
    __shared__ float rinvS[MODE == 2 ? 128 : 1];

    int tid = threadIdx.x;
    int b = blockIdx.y, e0 = blockIdx.x * 64;

    if (tid < 320) {
        int e = tid / 5, k = tid % 5;
        int eg = e0 + e;
        int id = (eg < E) ? gm[((size_t)b * E + eg) * 5 + k] : 0;
        idx[tid] = id;
        if (MODE == 1) {
            par[tid] = parent[b * EOUT + id];
            pv[tid] = pval[b * EOUT + id];
        }
    }
    if (MODE == 2 && tid < 128) {
        float s = stats_in[(b * 128 + tid) * 2 + 0];
        float q = stats_in[(b * 128 + tid) * 2 + 1];
        float invE = 1.0f / (float)EOUT;
        float mu = s * invE;
        muS[tid] = mu;
        rinvS[tid] = rsqrtf(q * invE - mu * mu + EPS);
    }
    __syncthreads();

    int l = tid & 63, w = tid >> 6;       // 8 waves
    int lr = l & 15, lg = l >> 4;
    int cg = tid & 7, eb = tid >> 3;      // stage: 8 ch-groups(4ch) x 64 edges = 512 slots
    bool evalid = (e0 + eb) < E;
    constexpr int XROW = (MODE == 0) ? CIN : 128;

    f32x4 acc[4];                          // et tiles; each wave owns 16 outs (o = w*16+lr)
#pragma unroll
    for (int et = 0; et < 4; ++et) acc[et] = (f32x4)0.f;

    uint2 g[5];
    auto loadG = [&](int chu) {
        int c0 = chu * 32 + cg * 4;
#pragma unroll
        for (int k = 0; k < 5; ++k) {
            g[k] = make_uint2(0u, 0u);
            if (evalid) {
                int s5 = eb * 5 + k;
                const ushort* src;
                if (MODE == 1) {
                    if (chu < NCH / 2) src = Xs + ((size_t)b * EIN + par[s5]) * 128 + c0;
                    else src = Aux + ((size_t)b * EOUT + idx[s5]) * 128 + (c0 - 128);
                } else {
                    src = Xs + ((size_t)b * E + idx[s5]) * XROW + c0;
                }
                g[k] = *reinterpret_cast<const uint2*>(src);
            }
        }
    };

    auto stageG = [&](int chu, ushort* gbuf) {
        float pvr[5];
        if (MODE == 1 && chu < NCH / 2) {
#pragma unroll
            for (int k = 0; k < 5; ++k) pvr[k] = pv[eb * 5 + k];
        }
#pragma unroll
        for (int j = 0; j < 4; ++j) {
            float f[5];
#pragma unroll
            for (int k = 0; k < 5; ++k) {
                uint32_t word = (j < 2) ? g[k].x : g[k].y;
                ushort h = (j & 1) ? (ushort)(word >> 16) : (ushort)(word & 0xffff);
                f[k] = bf2f(h);
            }
            if (MODE == 1 && chu < NCH / 2) {
#pragma unroll
                for (int k = 0; k < 5; ++k) f[k] *= pvr[k];
            } else if (MODE == 2) {
                int c = chu * 32 + cg * 4 + j;
                float mu = muS[c], rinv = rinvS[c];
#pragma unroll
                for (int k = 0; k < 5; ++k) {
                    float z = (f[k] - mu) * rinv;
                    f[k] = z > 0.f ? z : 0.f;
                }
            }
            uint4 v;
            v.x = pk2(f[0], f[1] + f[3]);
            v.y = pk2(f[2] + f[4], fabsf(f[1] - f[3]));
            v.z = pk2(fabsf(f[2] - f[4]), 0.f);
            v.w = 0u;
            *reinterpret_cast<uint4*>(gbuf + eb * LDW + (cg * 4 + j) * 8) = v;
        }
    };

    // depth-1 pipeline (R7/R12-proven fencing): stage chu -> barrier -> load chu+1 -> MFMA chu.
    loadG(0);
    for (int chu = 0; chu < NCH; ++chu) {
        ushort* gbuf = Gs + (chu & 1) * GSZ;
        stageG(chu, gbuf);
        __syncthreads();
        if (chu + 1 < NCH) loadG(chu + 1);
#pragma unroll
        for (int ks = 0; ks < 8; ++ks) {   // 8 K-steps of 32 k' per 32-ch chunk
            int ch16 = chu * 2 + (ks >> 2), ksl = ks & 3;
            // o = w*16+lr  ==  (w>>1)*32 + (w&1)*16 + lr  -> reuse R12's Wq layout
            const ushort* wbase =
                Wq + ((size_t)(((((w >> 1) * NCH16 + ch16) * 4 + ksl) * 2 + (w & 1)) * 64 + l)) * 8;
            bf16x8 bb = *reinterpret_cast<const bf16x8*>(wbase);
#pragma unroll
            for (int et = 0; et < 4; ++et) {
                bf16x8 a = *reinterpret_cast<const bf16x8*>(
                    gbuf + (et * 16 + lr) * LDW + ks * 32 + lg * 8);
                acc[et] = __builtin_amdgcn_mfma_f32_16x16x32_bf16(a, bb, acc[et], 0, 0, 0);
            }
        }
    }

    // epilogue: D frag: col = lane&15 (=o), row = (lane>>4)*4 + r (=edge)
    {
        int o = w * 16 + lr;
        float bv = bias[o];
        float s = 0.f, q = 0.f;
#pragma unroll
        for (int et = 0; et < 4; ++et) {
#pragma unroll
            for (int r = 0; r < 4; ++r) {
                int e = e0 + et * 16 + lg * 4 + r;
                if (e < E) {
                    float y = acc[et][r] + bv;
                    Out[((size_t)b * E + e) * 128 + o] = (ushort)bfr(y);
                    if (STATS) { s += y; q += y * y; }
                }
            }
        }
        if (STATS) {
            s += __shfl_xor(s, 16, 64); s += __shfl_xor(s, 32, 64);
            q += __shfl_xor(q, 16, 64); q += __shfl_xor(q, 32, 64);
            if (lg == 0) {
                atomicAdd(&stats_out[(b * 128 + o) * 2 + 0], s);
                atomicAdd(&stats_out[(b * 128 + o) * 2 + 1], q);
            }
        }
    }
}

// ---------- out[b][c][e] = relu( norm2(Y3) + relu(norm1(Y2)) ), bf16 -> f32 ch-major
__global__ void final_kernel(const ushort* __restrict__ Y3, const ushort* __restrict__ Y2,
                             const float* __restrict__ stats1, const float* __restrict__ stats2,
                             float* __restrict__ out, int E) {
    __shared__ float tile[32 * 129];
    int b = blockIdx.y;
    int e0 = blockIdx.x * 32;
    int tid = threadIdx.x;
    float invE = 1.0f / (float)E;
#pragma unroll
    for (int i = 0; i < 16; ++i) {
        int idx = i * 256 + tid;
        int c = idx & 127, el = idx >> 7;
        int e = e0 + el;
        float v = 0.f;
        if (e < E) {
            float s1 = stats1[(b * 128 + c) * 2 + 0], q1 = stats1[(b * 128 + c) * 2 + 1];
            float mu1 = s1 * invE, var1 = q1 * invE - mu1 * mu1;
            float s2 = stats2[(b * 128 + c) * 2 + 0], q2 = stats2[(b * 128 + c) * 2 + 1];
            float mu2 = s2 * invE, var2 = q2 * invE - mu2 * mu2;
            float x1 = (bf2f(Y2[((size_t)b * E + e) * 128 + c]) - mu1) * rsqrtf(var1 + EPS);
            x1 = x1 > 0.f ? x1 : 0.f;
            float z = (bf2f(Y3[((size_t)b * E + e) * 128 + c]) - mu2) * rsqrtf(var2 + EPS);
            v = z + x1;
            v = v > 0.f ? v : 0.f;
        }
        tile[el * 129 + c] = v;
    }
    __syncthreads();
#pragma unroll
    for (int i = 0; i < 16; ++i) {
        int idx = i * 256 + tid;
        int el = idx & 31, c = idx >> 5;
        int e = e0 + el;
        if (e < E) out[((size_t)b * 128 + c) * E + e] = tile[el * 129 + c];
    }
}

extern "C" void kernel_launch(void* const* d_in, const int* in_sizes, int n_in,
                              void* d_out, int out_size, void* d_ws, size_t ws_size,
                              hipStream_t stream) {
    const float* from_up   = (const float*)d_in[0];
    const float* from_down = (const float*)d_in[1];
    const float* unroll    = (const float*)d_in[2];
    const float* W_up      = (const float*)d_in[3];
    const float* b_up      = (const float*)d_in[4];
    const float* W1        = (const float*)d_in[5];
    const float* b1        = (const float*)d_in[6];
    const float* W2        = (const float*)d_in[7];
    const float* b2        = (const float*)d_in[8];
    const int* gemm_up     = (const int*)d_in[9];
    const int* gemm_post   = (const int*)d_in[10];
    float* out = (float*)d_out;

    float* ws = (float*)d_ws;
    size_t off = 0;
    auto alloc = [&](size_t n) { float* p = ws + off; off += n; return p; };
    ushort* FU_bf = (ushort*)alloc((size_t)NB * EIN * 256 / 2);   // [B][EIN][256] bf16
    ushort* FD_bf = (ushort*)alloc((size_t)NB * EOUT * 128 / 2);  // [B][EOUT][128] bf16
    ushort* Wq_up = (ushort*)alloc(131072);                       // frag order
    ushort* Wq_1  = (ushort*)alloc(131072);
    ushort* Wq_2  = (ushort*)alloc(65536);
    ushort* Y1_bf = (ushort*)alloc((size_t)NB * EIN * 128 / 2);
    ushort* Y2_bf = (ushort*)alloc((size_t)NB * EOUT * 128 / 2);
    ushort* Y3_bf = (ushort*)alloc((size_t)NB * EOUT * 128 / 2);
    float* stats  = alloc(1024);
    int*   parent = (int*)alloc(NB * EOUT);
    float* pval   = alloc(NB * EOUT);
    float* stats1 = stats, *stats2 = stats + 512;

    phase0_kernel<<<SCAN_B + FU_B + FD_B + WP_B + INIT_B, 256, 0, stream>>>(
        unroll, parent, pval, from_up, FU_bf, from_down, FD_bf,
        W_up, Wq_up, W1, Wq_1, W2, Wq_2, stats);

    // up conv: FU_bf -> Y1_bf
    conv_mfma<256, 0, false><<<dim3(71, NB), 512, 0, stream>>>(
        FU_bf, nullptr, gemm_up, nullptr, nullptr, nullptr, Wq_up, b_up, Y1_bf, nullptr, EIN);
    // conv1 (fused unpool+concat gather, fused stats1): -> Y2_bf
    conv_mfma<256, 1, true><<<dim3(141, NB), 512, 0, stream>>>(
        Y1_bf, FD_bf, gemm_post, parent, pval, nullptr, Wq_1, b1, Y2_bf, stats1, EOUT);
    // conv2 (fused norm+relu gather, fused stats2): -> Y3_bf
    conv_mfma<128, 2, true><<<dim3(141, NB), 512, 0, stream>>>(
        Y2_bf, nullptr, gemm_post, nullptr, nullptr, stats1, Wq_2, b2, Y3_bf, stats2, EOUT);
    // final: norm2 + residual + relu + transpose to [B][C][E] f32
    final_kernel<<<dim3(282, NB), 256, 0, stream>>>(Y3_bf, Y2_bf, stats1, stats2, out, EOUT);
}

// Round 14
// 110.324 us; speedup vs baseline: 1.7471x; 1.5033x over previous
//
#include <hip/hip_runtime.h>
#include <hip/hip_bf16.h>
#include <math.h>

#define NB 2
#define EIN 4500
#define EOUT 9000
#define EPS 1e-5f

typedef __attribute__((ext_vector_type(8))) short bf16x8;
typedef __attribute__((ext_vector_type(4))) float f32x4;

__device__ inline uint32_t bfr(float x) {
    uint32_t u = __float_as_uint(x);
    return (u + 0x7fffu + ((u >> 16) & 1u)) >> 16;
}
__device__ inline uint32_t pk2(float a, float b) {
    __hip_bfloat162 h = __float22bfloat162_rn(make_float2(a, b));   // v_cvt_pk_bf16_f32
    uint32_t u;
    __builtin_memcpy(&u, &h, 4);
    return u;
}
__device__ inline float bf2f(ushort u) { return __uint_as_float((uint32_t)u << 16); }

// ---------- W pack into per-wave fragment order (R12/R13 layout):
// Wq[((((w4*NCH16+g)*4+ks)*2+ot)*64+lane)*8 + f], o=w4*32+ot*16+(lane&15), c=g*16+ks*4+(lane>>4)
__device__ inline void wpack_frag(const float* __restrict__ W, ushort* __restrict__ Wq,
                                  int i, int CIN) {
    int lane = i & 63; int t = i >> 6;
    int ot = t & 1; t >>= 1;
    int ks = t & 3; t >>= 2;
    int NCH = CIN / 16;
    int ch = t % NCH, w = t / NCH;
    int o = w * 32 + ot * 16 + (lane & 15);
    int c = ch * 16 + ks * 4 + (lane >> 4);
    const float* src = W + ((size_t)o * CIN + c) * 5;
    uint4 v;
    v.x = pk2(src[0], src[1]);
    v.y = pk2(src[2], src[3]);
    v.z = pk2(src[4], 0.f);
    v.w = 0u;
    *reinterpret_cast<uint4*>(Wq + (size_t)i * 8) = v;
}

// ---------- tiled transpose f32 [R][C] -> bf16 [C][R] (one 32x32 tile per call)
__device__ inline void transpose_bf_body(float (*tile)[33], const float* __restrict__ in,
                                         ushort* __restrict__ out, int R, int C,
                                         int id, int nbx, int nby, int tid) {
    int bxt = id % nbx; int rest = id / nbx;
    int by = rest % nby; int b = rest / nby;
    int c0 = bxt * 32, r0 = by * 32;
    const float* inb = in + (size_t)b * R * C;
    ushort* outb = out + (size_t)b * C * R;
    int tx = tid & 31, ty = tid >> 5;   // 32 x 8
#pragma unroll
    for (int i = 0; i < 4; ++i) {
        int r = r0 + ty + i * 8, c = c0 + tx;
        if (r < R && c < C) tile[ty + i * 8][tx] = inb[(size_t)r * C + c];
    }
    __syncthreads();
#pragma unroll
    for (int i = 0; i < 4; ++i) {
        int c = c0 + ty + i * 8, r = r0 + tx;
        if (r < R && c < C) outb[(size_t)c * R + r] = (ushort)bfr(tile[tx][ty + i * 8]);
    }
}

// ---------- phase0: parent-extraction (adaptive probe) + transposes + wpack + stats-zero.
// Parent probe: each output edge's parent in a MeshUnpool matrix is 1-sparse per
// column; probe the natural candidate row eo/2 first (matches edge-split unpooling);
// fall back to a full column scan only if the probe misses (correct for any
// 1-sparse matrix; the fallback never triggers for standard unpool data).
#define GUESS_B 71    // ceil(18000/256)
#define FU_B 2256     // 141 x 8 x 2
#define FD_B 2256     // 282 x 4 x 2
#define WP_B 320      // 81920 / 256
#define INIT_B 1      // stats only (1024 floats)
__global__ __launch_bounds__(256) void phase0_kernel(
    const float* __restrict__ unroll, int* __restrict__ parent, float* __restrict__ pval,
    const float* __restrict__ from_up, ushort* __restrict__ FU,
    const float* __restrict__ from_down, ushort* __restrict__ FD,
    const float* __restrict__ W_up, ushort* __restrict__ Wq_up,
    const float* __restrict__ W1, ushort* __restrict__ Wq_1,
    const float* __restrict__ W2, ushort* __restrict__ Wq_2,
    float* __restrict__ stats) {
    __shared__ float tile[32][33];
    int bx = blockIdx.x, tid = threadIdx.x;
    if (bx < GUESS_B) {
        int i = bx * 256 + tid;          // i = b*EOUT + eo
        if (i < NB * EOUT) {
            int eo = i % EOUT;
            const float* mb = unroll + (size_t)(i / EOUT) * EIN * EOUT;
            int p = eo >> 1;
            float v = mb[(size_t)p * EOUT + eo];
            if (v == 0.f) {              // general 1-sparse fallback (never hit here)
                p = 0; v = 0.f;
                for (int ei = 0; ei < EIN; ++ei) {
                    float x = mb[(size_t)ei * EOUT + eo];
                    if (x != 0.f) { p = ei; v = x; break; }
                }
            }
            parent[i] = p;
            pval[i] = v;
        }
    } else if (bx < GUESS_B + FU_B) {
        transpose_bf_body(tile, from_up, FU, 256, EIN, bx - GUESS_B, 141, 8, tid);
    } else if (bx < GUESS_B + FU_B + FD_B) {
        transpose_bf_body(tile, from_down, FD, 128, EOUT, bx - (GUESS_B + FU_B), 282, 4, tid);
    } else if (bx < GUESS_B + FU_B + FD_B + WP_B) {
        int i = (bx - (GUESS_B + FU_B + FD_B)) * 256 + tid;
        if (i < 32768) wpack_frag(W_up, Wq_up, i, 256);
        else if (i < 65536) wpack_frag(W1, Wq_1, i - 32768, 256);
        else wpack_frag(W2, Wq_2, i - 65536, 128);
    } else {
#pragma unroll
        for (int j = 0; j < 4; ++j) stats[j * 256 + tid] = 0.f;
    }
}

// ---------- fused MFMA mesh conv (R13-identical): 64 edges x 128 outs, 8 waves,
// 32-ch chunks, double-buffered LDS, depth-1 prefetch, 1 barrier/chunk.
// MODE 0: gather bf16 Xs[id][c]   MODE 1: unpool(Y1)+concat(FD)   MODE 2: relu(norm(Y2))
template <int CIN, int MODE, bool STATS>
__global__ __launch_bounds__(512, 4) void conv_mfma(
    const ushort* __restrict__ Xs, const ushort* __restrict__ Aux,
    const int* __restrict__ gm, const int* __restrict__ parent,
    const float* __restrict__ pval, const float* __restrict__ stats_in,
    const ushort* __restrict__ Wq, const float* __restrict__ bias,
    ushort* __restrict__ Out, float* __restrict__ stats_out, int E) {
    constexpr int NCH16 = CIN / 16;   // Wq layout granularity
    constexpr int NCH = CIN / 32;     // 32-channel chunks
    constexpr int LDW = 264;          // 256 k' + 8 pad (bf16) per edge-row
    constexpr int GSZ = 64 * LDW;
    __shared__ __align__(16) ushort Gs[2 * GSZ];
    __shared__ int idx[320];
    __shared__ int par[MODE == 1 ? 320 : 1];
    __shared__ float pv[MODE == 1 ? 320 : 1];
    __shared__ float muS[MODE == 2 ? 128 : 1];
    __shared__ float rinvS[MODE == 2 ? 128 : 1];

    int tid = threadIdx.x;
    int b = blockIdx.y, e0 = blockIdx.x * 64;

    if (tid < 320) {
        int e = tid / 5, k = tid % 5;
        int eg = e0 + e;
        int id = (eg < E) ? gm[((size_t)b * E + eg) * 5 + k] : 0;
        idx[tid] = id;
        if (MODE == 1) {
            par[tid] = parent[b * EOUT + id];
            pv[tid] = pval[b * EOUT + id];
        }
    }
    if (MODE == 2 && tid < 128) {
        float s = stats_in[(b * 128 + tid) * 2 + 0];
        float q = stats_in[(b * 128 + tid) * 2 + 1];
        float invE = 1.0f / (float)EOUT;
        float mu = s * invE;
        muS[tid] = mu;
        rinvS[tid] = rsqrtf(q * invE - mu * mu + EPS);
    }
    __syncthreads();

    int l = tid & 63, w = tid >> 6;       // 8 waves
    int lr = l & 15, lg = l >> 4;
    int cg = tid & 7, eb = tid >> 3;      // stage: 8 ch-groups(4ch) x 64 edges = 512 slots
    bool evalid = (e0 + eb) < E;
    constexpr int XROW = (MODE == 0) ? CIN : 128;

    f32x4 acc[4];                          // each wave owns 16 outs (o = w*16+lr)
#pragma unroll
    for (int et = 0; et < 4; ++et) acc[et] = (f32x4)0.f;

    uint2 g[5];
    auto loadG = [&](int chu) {
        int c0 = chu * 32 + cg * 4;
#pragma unroll
        for (int k = 0; k < 5; ++k) {
            g[k] = make_uint2(0u, 0u);
            if (evalid) {
                int s5 = eb * 5 + k;
                const ushort* src;
                if (MODE == 1) {
                    if (chu < NCH / 2) src = Xs + ((size_t)b * EIN + par[s5]) * 128 + c0;
                    else src = Aux + ((size_t)b * EOUT + idx[s5]) * 128 + (c0 - 128);
                } else {
                    src = Xs + ((size_t)b * E + idx[s5]) * XROW + c0;
                }
                g[k] = *reinterpret_cast<const uint2*>(src);
            }
        }
    };

    auto stageG = [&](int chu, ushort* gbuf) {
        float pvr[5];
        if (MODE == 1 && chu < NCH / 2) {
#pragma unroll
            for (int k = 0; k < 5; ++k) pvr[k] = pv[eb * 5 + k];
        }
#pragma unroll
        for (int j = 0; j < 4; ++j) {
            float f[5];
#pragma unroll
            for (int k = 0; k < 5; ++k) {
                uint32_t word = (j < 2) ? g[k].x : g[k].y;
                ushort h = (j & 1) ? (ushort)(word >> 16) : (ushort)(word & 0xffff);
                f[k] = bf2f(h);
            }
            if (MODE == 1 && chu < NCH / 2) {
#pragma unroll
                for (int k = 0; k < 5; ++k) f[k] *= pvr[k];
            } else if (MODE == 2) {
                int c = chu * 32 + cg * 4 + j;
                float mu = muS[c], rinv = rinvS[c];
#pragma unroll
                for (int k = 0; k < 5; ++k) {
                    float z = (f[k] - mu) * rinv;
                    f[k] = z > 0.f ? z : 0.f;
                }
            }
            uint4 v;
            v.x = pk2(f[0], f[1] + f[3]);
            v.y = pk2(f[2] + f[4], fabsf(f[1] - f[3]));
            v.z = pk2(fabsf(f[2] - f[4]), 0.f);
            v.w = 0u;
            *reinterpret_cast<uint4*>(gbuf + eb * LDW + (cg * 4 + j) * 8) = v;
        }
    };

    // depth-1 pipeline: stage chu -> barrier -> load chu+1 -> MFMA chu.
    loadG(0);
    for (int chu = 0; chu < NCH; ++chu) {
        ushort* gbuf = Gs + (chu & 1) * GSZ;
        stageG(chu, gbuf);
        __syncthreads();
        if (chu + 1 < NCH) loadG(chu + 1);
#pragma unroll
        for (int ks = 0; ks < 8; ++ks) {   // 8 K-steps of 32 k' per 32-ch chunk
            int ch16 = chu * 2 + (ks >> 2), ksl = ks & 3;
            const ushort* wbase =
                Wq + ((size_t)(((((w >> 1) * NCH16 + ch16) * 4 + ksl) * 2 + (w & 1)) * 64 + l)) * 8;
            bf16x8 bb = *reinterpret_cast<const bf16x8*>(wbase);
#pragma unroll
            for (int et = 0; et < 4; ++et) {
                bf16x8 a = *reinterpret_cast<const bf16x8*>(
                    gbuf + (et * 16 + lr) * LDW + ks * 32 + lg * 8);
                acc[et] = __builtin_amdgcn_mfma_f32_16x16x32_bf16(a, bb, acc[et], 0, 0, 0);
            }
        }
    }

    // epilogue: D frag: col = lane&15 (=o), row = (lane>>4)*4 + r (=edge)
    {
        int o = w * 16 + lr;
        float bv = bias[o];
        float s = 0.f, q = 0.f;
#pragma unroll
        for (int et = 0; et < 4; ++et) {
#pragma unroll
            for (int r = 0; r < 4; ++r) {
                int e = e0 + et * 16 + lg * 4 + r;
                if (e < E) {
                    float y = acc[et][r] + bv;
                    Out[((size_t)b * E + e) * 128 + o] = (ushort)bfr(y);
                    if (STATS) { s += y; q += y * y; }
                }
            }
        }
        if (STATS) {
            s += __shfl_xor(s, 16, 64); s += __shfl_xor(s, 32, 64);
            q += __shfl_xor(q, 16, 64); q += __shfl_xor(q, 32, 64);
            if (lg == 0) {
                atomicAdd(&stats_out[(b * 128 + o) * 2 + 0], s);
                atomicAdd(&stats_out[(b * 128 + o) * 2 + 1], q);
            }
        }
    }
}

// ---------- out[b][c][e] = relu( norm2(Y3) + relu(norm1(Y2)) ), bf16 -> f32 ch-major
__global__ void final_kernel(const ushort* __restrict__ Y3, const ushort* __restrict__ Y2,
                             const float* __restrict__ stats1, const float* __restrict__ stats2,
                             float* __restrict__ out, int E) {
    __shared__ float tile[32 * 129];
    int b = blockIdx.y;
    int e0 = blockIdx.x * 32;
    int tid = threadIdx.x;
    float invE = 1.0f / (float)E;
#pragma unroll
    for (int i = 0; i < 16; ++i) {
        int idx = i * 256 + tid;
        int c = idx & 127, el = idx >> 7;
        int e = e0 + el;
        float v = 0.f;
        if (e < E) {
            float s1 = stats1[(b * 128 + c) * 2 + 0], q1 = stats1[(b * 128 + c) * 2 + 1];
            float mu1 = s1 * invE, var1 = q1 * invE - mu1 * mu1;
            float s2 = stats2[(b * 128 + c) * 2 + 0], q2 = stats2[(b * 128 + c) * 2 + 1];
            float mu2 = s2 * invE, var2 = q2 * invE - mu2 * mu2;
            float x1 = (bf2f(Y2[((size_t)b * E + e) * 128 + c]) - mu1) * rsqrtf(var1 + EPS);
            x1 = x1 > 0.f ? x1 : 0.f;
            float z = (bf2f(Y3[((size_t)b * E + e) * 128 + c]) - mu2) * rsqrtf(var2 + EPS);
            v = z + x1;
            v = v > 0.f ? v : 0.f;
        }
        tile[el * 129 + c] = v;
    }
    __syncthreads();
#pragma unroll
    for (int i = 0; i < 16; ++i) {
        int idx = i * 256 + tid;
        int el = idx & 31, c = idx >> 5;
        int e = e0 + el;
        if (e < E) out[((size_t)b * 128 + c) * E + e] = tile[el * 129 + c];
    }
}

extern "C" void kernel_launch(void* const* d_in, const int* in_sizes, int n_in,
                              void* d_out, int out_size, void* d_ws, size_t ws_size,
                              hipStream_t stream) {
    const float* from_up   = (const float*)d_in[0];
    const float* from_down = (const float*)d_in[1];
    const float* unroll    = (const float*)d_in[2];
    const float* W_up      = (const float*)d_in[3];
    const float* b_up      = (const float*)d_in[4];
    const float* W1        = (const float*)d_in[5];
    const float* b1        = (const float*)d_in[6];
    const float* W2        = (const float*)d_in[7];
    const float* b2        = (const float*)d_in[8];
    const int* gemm_up     = (const int*)d_in[9];
    const int* gemm_post   = (const int*)d_in[10];
    float* out = (float*)d_out;

    float* ws = (float*)d_ws;
    size_t off = 0;
    auto alloc = [&](size_t n) { float* p = ws + off; off += n; return p; };
    ushort* FU_bf = (ushort*)alloc((size_t)NB * EIN * 256 / 2);   // [B][EIN][256] bf16
    ushort* FD_bf = (ushort*)alloc((size_t)NB * EOUT * 128 / 2);  // [B][EOUT][128] bf16
    ushort* Wq_up = (ushort*)alloc(131072);                       // frag order
    ushort* Wq_1  = (ushort*)alloc(131072);
    ushort* Wq_2  = (ushort*)alloc(65536);
    ushort* Y1_bf = (ushort*)alloc((size_t)NB * EIN * 128 / 2);
    ushort* Y2_bf = (ushort*)alloc((size_t)NB * EOUT * 128 / 2);
    ushort* Y3_bf = (ushort*)alloc((size_t)NB * EOUT * 128 / 2);
    float* stats  = alloc(1024);
    int*   parent = (int*)alloc(NB * EOUT);
    float* pval   = alloc(NB * EOUT);
    float* stats1 = stats, *stats2 = stats + 512;

    phase0_kernel<<<GUESS_B + FU_B + FD_B + WP_B + INIT_B, 256, 0, stream>>>(
        unroll, parent, pval, from_up, FU_bf, from_down, FD_bf,
        W_up, Wq_up, W1, Wq_1, W2, Wq_2, stats);

    // up conv: FU_bf -> Y1_bf
    conv_mfma<256, 0, false><<<dim3(71, NB), 512, 0, stream>>>(
        FU_bf, nullptr, gemm_up, nullptr, nullptr, nullptr, Wq_up, b_up, Y1_bf, nullptr, EIN);
    // conv1 (fused unpool+concat gather, fused stats1): -> Y2_bf
    conv_mfma<256, 1, true><<<dim3(141, NB), 512, 0, stream>>>(
        Y1_bf, FD_bf, gemm_post, parent, pval, nullptr, Wq_1, b1, Y2_bf, stats1, EOUT);
    // conv2 (fused norm+relu gather, fused stats2): -> Y3_bf
    conv_mfma<128, 2, true><<<dim3(141, NB), 512, 0, stream>>>(
        Y2_bf, nullptr, gemm_post, nullptr, nullptr, stats1, Wq_2, b2, Y3_bf, stats2, EOUT);
    // final: norm2 + residual + relu + transpose to [B][C][E] f32
    final_kernel<<<dim3(282, NB), 256, 0, stream>>>(Y3_bf, Y2_bf, stats1, stats2, out, EOUT);
}

// Round 15
// 98.808 us; speedup vs baseline: 1.9507x; 1.1166x over previous
//
#include <hip/hip_runtime.h>
#include <hip/hip_bf16.h>
#include <math.h>

#define NB 2
#define EIN 4500
#define EOUT 9000
#define EPS 1e-5f

typedef __attribute__((ext_vector_type(8))) short bf16x8;
typedef __attribute__((ext_vector_type(4))) float f32x4;

__device__ inline uint32_t bfr(float x) {
    uint32_t u = __float_as_uint(x);
    return (u + 0x7fffu + ((u >> 16) & 1u)) >> 16;
}
__device__ inline uint32_t pk2(float a, float b) {
    __hip_bfloat162 h = __float22bfloat162_rn(make_float2(a, b));   // v_cvt_pk_bf16_f32
    uint32_t u;
    __builtin_memcpy(&u, &h, 4);
    return u;
}
__device__ inline float bf2f(ushort u) { return __uint_as_float((uint32_t)u << 16); }

// ---------- W pack, DENSE k' = c*5 + f (no pad slots):
// Wq[((og*NSTEP + st)*64 + lane)*8 + f8]: o = og*16 + (lane&15),
// k' = st*32 + (lane>>4)*8 + f8, (c, feat) = (k'/5, k'%5).
__device__ inline void wpack_frag(const float* __restrict__ W, ushort* __restrict__ Wq,
                                  int i, int CIN) {
    int lane = i & 63; int t = i >> 6;
    int NSTEP = CIN * 5 / 32;
    int st = t % NSTEP, og = t / NSTEP;
    int o = og * 16 + (lane & 15);
    int k0 = st * 32 + (lane >> 4) * 8;
    uint32_t u[4];
#pragma unroll
    for (int q = 0; q < 4; ++q) {
        int ka = k0 + 2 * q, kb = ka + 1;
        float va = W[((size_t)o * CIN + ka / 5) * 5 + ka % 5];
        float vb = W[((size_t)o * CIN + kb / 5) * 5 + kb % 5];
        u[q] = pk2(va, vb);
    }
    *reinterpret_cast<uint4*>(Wq + (size_t)i * 8) = make_uint4(u[0], u[1], u[2], u[3]);
}

// ---------- tiled transpose f32 [R][C] -> bf16 [C][R] (one 32x32 tile per call)
__device__ inline void transpose_bf_body(float (*tile)[33], const float* __restrict__ in,
                                         ushort* __restrict__ out, int R, int C,
                                         int id, int nbx, int nby, int tid) {
    int bxt = id % nbx; int rest = id / nbx;
    int by = rest % nby; int b = rest / nby;
    int c0 = bxt * 32, r0 = by * 32;
    const float* inb = in + (size_t)b * R * C;
    ushort* outb = out + (size_t)b * C * R;
    int tx = tid & 31, ty = tid >> 5;   // 32 x 8
#pragma unroll
    for (int i = 0; i < 4; ++i) {
        int r = r0 + ty + i * 8, c = c0 + tx;
        if (r < R && c < C) tile[ty + i * 8][tx] = inb[(size_t)r * C + c];
    }
    __syncthreads();
#pragma unroll
    for (int i = 0; i < 4; ++i) {
        int c = c0 + ty + i * 8, r = r0 + tx;
        if (r < R && c < C) outb[(size_t)c * R + r] = (ushort)bfr(tile[tx][ty + i * 8]);
    }
}

// ---------- phase0: parent probe + transposes + wpack + stats-zero (R14 structure).
#define GUESS_B 71    // ceil(18000/256)
#define FU_B 2256     // 141 x 8 x 2
#define FD_B 2256     // 282 x 4 x 2
#define WP_B 200      // 51200 items / 256
#define INIT_B 1      // stats only (1024 floats)
__global__ __launch_bounds__(256) void phase0_kernel(
    const float* __restrict__ unroll, int* __restrict__ parent, float* __restrict__ pval,
    const float* __restrict__ from_up, ushort* __restrict__ FU,
    const float* __restrict__ from_down, ushort* __restrict__ FD,
    const float* __restrict__ W_up, ushort* __restrict__ Wq_up,
    const float* __restrict__ W1, ushort* __restrict__ Wq_1,
    const float* __restrict__ W2, ushort* __restrict__ Wq_2,
    float* __restrict__ stats) {
    __shared__ float tile[32][33];
    int bx = blockIdx.x, tid = threadIdx.x;
    if (bx < GUESS_B) {
        int i = bx * 256 + tid;          // i = b*EOUT + eo
        if (i < NB * EOUT) {
            int eo = i % EOUT;
            const float* mb = unroll + (size_t)(i / EOUT) * EIN * EOUT;
            int p = eo >> 1;
            float v = mb[(size_t)p * EOUT + eo];
            if (v == 0.f) {              // general 1-sparse fallback (never hit here)
                p = 0; v = 0.f;
                for (int ei = 0; ei < EIN; ++ei) {
                    float x = mb[(size_t)ei * EOUT + eo];
                    if (x != 0.f) { p = ei; v = x; break; }
                }
            }
            parent[i] = p;
            pval[i] = v;
        }
    } else if (bx < GUESS_B + FU_B) {
        transpose_bf_body(tile, from_up, FU, 256, EIN, bx - GUESS_B, 141, 8, tid);
    } else if (bx < GUESS_B + FU_B + FD_B) {
        transpose_bf_body(tile, from_down, FD, 128, EOUT, bx - (GUESS_B + FU_B), 282, 4, tid);
    } else if (bx < GUESS_B + FU_B + FD_B + WP_B) {
        int i = (bx - (GUESS_B + FU_B + FD_B)) * 256 + tid;
        if (i < 20480) wpack_frag(W_up, Wq_up, i, 256);              // 8og x 40st x 64
        else if (i < 40960) wpack_frag(W1, Wq_1, i - 20480, 256);
        else wpack_frag(W2, Wq_2, i - 40960, 128);                   // 8og x 20st x 64
    } else {
#pragma unroll
        for (int j = 0; j < 4; ++j) stats[j * 256 + tid] = 0.f;
    }
}

// ---------- fused MFMA mesh conv: 64 edges x 128 outs, 8 waves (512 thr),
// DENSE K' = CIN*5; 32-ch chunks (=5 K-steps); dbuf LDS; depth-1 prefetch.
// MODE 0: gather bf16 Xs[id][c]   MODE 1: unpool(Y1)+concat(FD)   MODE 2: relu(norm(Y2))
template <int CIN, int MODE, bool STATS>
__global__ __launch_bounds__(512, 4) void conv_mfma(
    const ushort* __restrict__ Xs, const ushort* __restrict__ Aux,
    const int* __restrict__ gm, const int* __restrict__ parent,
    const float* __restrict__ pval, const float* __restrict__ stats_in,
    const ushort* __restrict__ Wq, const float* __restrict__ bias,
    ushort* __restrict__ Out, float* __restrict__ stats_out, int E) {
    constexpr int NCH = CIN / 32;         // 32-channel chunks
    constexpr int NSTEP = CIN * 5 / 32;   // total K-steps (dense)
    constexpr int LDW = 168;              // 160 k' + 8 pad (bf16); 336B row, 16B-aligned
    constexpr int GSZ = 64 * LDW;
    __shared__ __align__(16) ushort Gs[2 * GSZ];
    __shared__ int idx[320];
    __shared__ int par[MODE == 1 ? 320 : 1];
    __shared__ float pv[MODE == 1 ? 320 : 1];
    __shared__ float muS[MODE == 2 ? 128 : 1];
    __shared__ float rinvS[MODE == 2 ? 128 : 1];

    int tid = threadIdx.x;
    int b = blockIdx.y, e0 = blockIdx.x * 64;

    if (tid < 320) {
        int e = tid / 5, k = tid % 5;
        int eg = e0 + e;
        int id = (eg < E) ? gm[((size_t)b * E + eg) * 5 + k] : 0;
        idx[tid] = id;
        if (MODE == 1) {
            par[tid] = parent[b * EOUT + id];
            pv[tid] = pval[b * EOUT + id];
        }
    }
    if (MODE == 2 && tid < 128) {
        float s = stats_in[(b * 128 + tid) * 2 + 0];
        float q = stats_in[(b * 128 + tid) * 2 + 1];
        float invE = 1.0f / (float)EOUT;
        float mu = s * invE;
        muS[tid] = mu;
        rinvS[tid] = rsqrtf(q * invE - mu * mu + EPS);
    }
    __syncthreads();

    int l = tid & 63, w = tid >> 6;       // 8 waves; wave owns o = w*16 + lr
    int lr = l & 15, lg = l >> 4;
    int cg = tid & 7, eb = tid >> 3;      // stage: 8 ch-groups(4ch) x 64 edges
    bool evalid = (e0 + eb) < E;
    constexpr int XROW = (MODE == 0) ? CIN : 128;

    f32x4 acc[4];
#pragma unroll
    for (int et = 0; et < 4; ++et) acc[et] = (f32x4)0.f;

    uint2 g[5];
    auto loadG = [&](int chu) {
        int c0 = chu * 32 + cg * 4;
#pragma unroll
        for (int k = 0; k < 5; ++k) {
            g[k] = make_uint2(0u, 0u);
            if (evalid) {
                int s5 = eb * 5 + k;
                const ushort* src;
                if (MODE == 1) {
                    if (chu < NCH / 2) src = Xs + ((size_t)b * EIN + par[s5]) * 128 + c0;
                    else src = Aux + ((size_t)b * EOUT + idx[s5]) * 128 + (c0 - 128);
                } else {
                    src = Xs + ((size_t)b * E + idx[s5]) * XROW + c0;
                }
                g[k] = *reinterpret_cast<const uint2*>(src);
            }
        }
    };

    // stage: 4 channels/thread -> 20 dense k'-slots (40B) at row offset cg*40B
    auto stageG = [&](int chu, ushort* gbuf) {
        float pvr[5];
        if (MODE == 1 && chu < NCH / 2) {
#pragma unroll
            for (int k = 0; k < 5; ++k) pvr[k] = pv[eb * 5 + k];
        }
        float fa[20];
#pragma unroll
        for (int j = 0; j < 4; ++j) {
            float f[5];
#pragma unroll
            for (int k = 0; k < 5; ++k) {
                uint32_t word = (j < 2) ? g[k].x : g[k].y;
                ushort h = (j & 1) ? (ushort)(word >> 16) : (ushort)(word & 0xffff);
                f[k] = bf2f(h);
            }
            if (MODE == 1 && chu < NCH / 2) {
#pragma unroll
                for (int k = 0; k < 5; ++k) f[k] *= pvr[k];
            } else if (MODE == 2) {
                int c = chu * 32 + cg * 4 + j;
                float mu = muS[c], rinv = rinvS[c];
#pragma unroll
                for (int k = 0; k < 5; ++k) {
                    float z = (f[k] - mu) * rinv;
                    f[k] = z > 0.f ? z : 0.f;
                }
            }
            fa[j * 5 + 0] = f[0];
            fa[j * 5 + 1] = f[1] + f[3];
            fa[j * 5 + 2] = f[2] + f[4];
            fa[j * 5 + 3] = fabsf(f[1] - f[3]);
            fa[j * 5 + 4] = fabsf(f[2] - f[4]);
        }
        uint32_t u[10];
#pragma unroll
        for (int q = 0; q < 10; ++q) u[q] = pk2(fa[2 * q], fa[2 * q + 1]);
        ushort* dst = gbuf + eb * LDW + cg * 20;
#pragma unroll
        for (int q = 0; q < 5; ++q)
            *reinterpret_cast<uint2*>(dst + q * 4) = make_uint2(u[2 * q], u[2 * q + 1]);
    };

    // depth-1 pipeline (proven fencing): stage chu -> barrier -> load chu+1 -> MFMA chu.
    loadG(0);
    for (int chu = 0; chu < NCH; ++chu) {
        ushort* gbuf = Gs + (chu & 1) * GSZ;
        stageG(chu, gbuf);
        __syncthreads();
        if (chu + 1 < NCH) loadG(chu + 1);
#pragma unroll
        for (int ks = 0; ks < 5; ++ks) {   // 5 K-steps of 32 k' per 32-ch chunk
            const ushort* wbase =
                Wq + ((size_t)(w * NSTEP + chu * 5 + ks) * 64 + l) * 8;
            bf16x8 bb = *reinterpret_cast<const bf16x8*>(wbase);
#pragma unroll
            for (int et = 0; et < 4; ++et) {
                bf16x8 a = *reinterpret_cast<const bf16x8*>(
                    gbuf + (et * 16 + lr) * LDW + ks * 32 + lg * 8);
                acc[et] = __builtin_amdgcn_mfma_f32_16x16x32_bf16(a, bb, acc[et], 0, 0, 0);
            }
        }
    }

    // epilogue: D frag: col = lane&15 (=o), row = (lane>>4)*4 + r (=edge)
    {
        int o = w * 16 + lr;
        float bv = bias[o];
        float s = 0.f, q = 0.f;
#pragma unroll
        for (int et = 0; et < 4; ++et) {
#pragma unroll
            for (int r = 0; r < 4; ++r) {
                int e = e0 + et * 16 + lg * 4 + r;
                if (e < E) {
                    float y = acc[et][r] + bv;
                    Out[((size_t)b * E + e) * 128 + o] = (ushort)bfr(y);
                    if (STATS) { s += y; q += y * y; }
                }
            }
        }
        if (STATS) {
            s += __shfl_xor(s, 16, 64); s += __shfl_xor(s, 32, 64);
            q += __shfl_xor(q, 16, 64); q += __shfl_xor(q, 32, 64);
            if (lg == 0) {
                atomicAdd(&stats_out[(b * 128 + o) * 2 + 0], s);
                atomicAdd(&stats_out[(b * 128 + o) * 2 + 1], q);
            }
        }
    }
}

// ---------- out[b][c][e] = relu( norm2(Y3) + relu(norm1(Y2)) ), bf16 -> f32 ch-major
__global__ void final_kernel(const ushort* __restrict__ Y3, const ushort* __restrict__ Y2,
                             const float* __restrict__ stats1, const float* __restrict__ stats2,
                             float* __restrict__ out, int E) {
    __shared__ float tile[32 * 129];
    int b = blockIdx.y;
    int e0 = blockIdx.x * 32;
    int tid = threadIdx.x;
    float invE = 1.0f / (float)E;
#pragma unroll
    for (int i = 0; i < 16; ++i) {
        int idx = i * 256 + tid;
        int c = idx & 127, el = idx >> 7;
        int e = e0 + el;
        float v = 0.f;
        if (e < E) {
            float s1 = stats1[(b * 128 + c) * 2 + 0], q1 = stats1[(b * 128 + c) * 2 + 1];
            float mu1 = s1 * invE, var1 = q1 * invE - mu1 * mu1;
            float s2 = stats2[(b * 128 + c) * 2 + 0], q2 = stats2[(b * 128 + c) * 2 + 1];
            float mu2 = s2 * invE, var2 = q2 * invE - mu2 * mu2;
            float x1 = (bf2f(Y2[((size_t)b * E + e) * 128 + c]) - mu1) * rsqrtf(var1 + EPS);
            x1 = x1 > 0.f ? x1 : 0.f;
            float z = (bf2f(Y3[((size_t)b * E + e) * 128 + c]) - mu2) * rsqrtf(var2 + EPS);
            v = z + x1;
            v = v > 0.f ? v : 0.f;
        }
        tile[el * 129 + c] = v;
    }
    __syncthreads();
#pragma unroll
    for (int i = 0; i < 16; ++i) {
        int idx = i * 256 + tid;
        int el = idx & 31, c = idx >> 5;
        int e = e0 + el;
        if (e < E) out[((size_t)b * 128 + c) * E + e] = tile[el * 129 + c];
    }
}

extern "C" void kernel_launch(void* const* d_in, const int* in_sizes, int n_in,
                              void* d_out, int out_size, void* d_ws, size_t ws_size,
                              hipStream_t stream) {
    const float* from_up   = (const float*)d_in[0];
    const float* from_down = (const float*)d_in[1];
    const float* unroll    = (const float*)d_in[2];
    const float* W_up      = (const float*)d_in[3];
    const float* b_up      = (const float*)d_in[4];
    const float* W1        = (const float*)d_in[5];
    const float* b1        = (const float*)d_in[6];
    const float* W2        = (const float*)d_in[7];
    const float* b2        = (const float*)d_in[8];
    const int* gemm_up     = (const int*)d_in[9];
    const int* gemm_post   = (const int*)d_in[10];
    float* out = (float*)d_out;

    float* ws = (float*)d_ws;
    size_t off = 0;
    auto alloc = [&](size_t n) { float* p = ws + off; off += n; return p; };
    ushort* FU_bf = (ushort*)alloc((size_t)NB * EIN * 256 / 2);   // [B][EIN][256] bf16
    ushort* FD_bf = (ushort*)alloc((size_t)NB * EOUT * 128 / 2);  // [B][EOUT][128] bf16
    ushort* Wq_up = (ushort*)alloc(81920);                        // 128 x 1280 bf16 dense
    ushort* Wq_1  = (ushort*)alloc(81920);
    ushort* Wq_2  = (ushort*)alloc(40960);                        // 128 x 640
    ushort* Y1_bf = (ushort*)alloc((size_t)NB * EIN * 128 / 2);
    ushort* Y2_bf = (ushort*)alloc((size_t)NB * EOUT * 128 / 2);
    ushort* Y3_bf = (ushort*)alloc((size_t)NB * EOUT * 128 / 2);
    float* stats  = alloc(1024);
    int*   parent = (int*)alloc(NB * EOUT);
    float* pval   = alloc(NB * EOUT);
    float* stats1 = stats, *stats2 = stats + 512;

    phase0_kernel<<<GUESS_B + FU_B + FD_B + WP_B + INIT_B, 256, 0, stream>>>(
        unroll, parent, pval, from_up, FU_bf, from_down, FD_bf,
        W_up, Wq_up, W1, Wq_1, W2, Wq_2, stats);

    // up conv: FU_bf -> Y1_bf
    conv_mfma<256, 0, false><<<dim3(71, NB), 512, 0, stream>>>(
        FU_bf, nullptr, gemm_up, nullptr, nullptr, nullptr, Wq_up, b_up, Y1_bf, nullptr, EIN);
    // conv1 (fused unpool+concat gather, fused stats1): -> Y2_bf
    conv_mfma<256, 1, true><<<dim3(141, NB), 512, 0, stream>>>(
        Y1_bf, FD_bf, gemm_post, parent, pval, nullptr, Wq_1, b1, Y2_bf, stats1, EOUT);
    // conv2 (fused norm+relu gather, fused stats2): -> Y3_bf
    conv_mfma<128, 2, true><<<dim3(141, NB), 512, 0, stream>>>(
        Y2_bf, nullptr, gemm_post, nullptr, nullptr, stats1, Wq_2, b2, Y3_bf, stats2, EOUT);
    // final: norm2 + residual + relu + transpose to [B][C][E] f32
    final_kernel<<<dim3(282, NB), 256, 0, stream>>>(Y3_bf, Y2_bf, stats1, stats2, out, EOUT);
}